// Round 4
// baseline (1576.916 us; speedup 1.0000x reference)
//
#include <hip/hip_runtime.h>
#include <hip/hip_bf16.h>

typedef unsigned short u16;
typedef unsigned int   u32;

#define N_NODES 100000
#define N_EDGES 1600000
#define NQ      (N_EDGES / 4)     // 400000 uint4 quads per endpoint array
#define SLICE   12500             // N_NODES / 8
#define BPG     96                // blocks per dst-slice group in build kernels

#define NS      50                // nodes per dst-slice in aggregation
#define NSLICES (N_NODES / NS)    // 2000 blocks per agg pass
#define LDW     65                // LDS row stride in dwords (65 mod 32 = 1 -> bank spread)

__device__ __forceinline__ float bf2f(u16 u) {
    union { u32 i; float f; } c; c.i = ((u32)u) << 16; return c.f;
}
__device__ __forceinline__ u16 f2bf(float f) {
    union { float f; u32 i; } c; c.f = f;
    u32 u = c.i;
    u += 0x7fffu + ((u >> 16) & 1u);   // RNE
    return (u16)(u >> 16);
}
__device__ __forceinline__ void up8(uint4 d, float* f) {
    f[0] = bf2f((u16)(d.x & 0xffffu)); f[1] = bf2f((u16)(d.x >> 16));
    f[2] = bf2f((u16)(d.y & 0xffffu)); f[3] = bf2f((u16)(d.y >> 16));
    f[4] = bf2f((u16)(d.z & 0xffffu)); f[5] = bf2f((u16)(d.z >> 16));
    f[6] = bf2f((u16)(d.w & 0xffffu)); f[7] = bf2f((u16)(d.w >> 16));
}

// ---------------- flatten edge_index to int32 src/dst (dtype probe inlined) ----------------
__global__ __launch_bounds__(256) void k_convert(const u32* __restrict__ ei,
                                                 uint4* __restrict__ src4,
                                                 uint4* __restrict__ dst4) {
    __shared__ int sflag;
    if (threadIdx.x == 0) {
        u32 h = ei[1] | ei[3] | ei[5] | ei[7];
        sflag = (h == 0u) ? 1 : 0;   // int64 layout: (lo,hi) pairs, hi==0
    }
    __syncthreads();
    int q = blockIdx.x * 256 + threadIdx.x;
    if (q >= NQ) return;
    const uint4* e4 = (const uint4*)ei;
    if (sflag) {
        uint4 a = e4[2 * q],          b = e4[2 * q + 1];
        src4[q] = make_uint4(a.x, a.z, b.x, b.z);
        uint4 c = e4[2 * NQ + 2 * q], d = e4[2 * NQ + 2 * q + 1];
        dst4[q] = make_uint4(c.x, c.z, d.x, d.z);
    } else {
        src4[q] = e4[q];
        dst4[q] = e4[NQ + q];
    }
}

// ---------------- degree (dst-slice partitioned; slice = blockIdx&7 ~ XCD) ----------------
__global__ __launch_bounds__(256) void k_degree(const uint4* __restrict__ dst4,
                                                int* __restrict__ deg) {
    const int g = blockIdx.x & 7, bb = blockIdx.x >> 3;
    const int lo = g * SLICE, hi = lo + SLICE;
    for (int q = bb * 256 + threadIdx.x; q < NQ; q += BPG * 256) {
        uint4 d = dst4[q];
        if ((int)d.x >= lo && (int)d.x < hi) atomicAdd(&deg[d.x], 1);
        if ((int)d.y >= lo && (int)d.y < hi) atomicAdd(&deg[d.y], 1);
        if ((int)d.z >= lo && (int)d.z < hi) atomicAdd(&deg[d.z], 1);
        if ((int)d.w >= lo && (int)d.w < hi) atomicAdd(&deg[d.w], 1);
    }
}

// ---------------- exclusive scan over degrees ----------------
__global__ void k_scan_part(const int* __restrict__ deg, int* __restrict__ rowstart,
                            int* __restrict__ bsums) {
    __shared__ int sh[256];
    const int t = threadIdx.x, b = blockIdx.x;
    const int base = b * 2048 + t * 8;
    int v[8]; int s = 0;
#pragma unroll
    for (int i = 0; i < 8; i++) {
        int idx = base + i;
        v[i] = (idx < N_NODES) ? deg[idx] : 0;
        s += v[i];
    }
    sh[t] = s;
    __syncthreads();
    for (int d = 1; d < 256; d <<= 1) {
        int x = (t >= d) ? sh[t - d] : 0;
        __syncthreads();
        sh[t] += x;
        __syncthreads();
    }
    int acc = sh[t] - s;
#pragma unroll
    for (int i = 0; i < 8; i++) {
        int idx = base + i;
        if (idx < N_NODES) rowstart[idx] = acc;
        acc += v[i];
    }
    if (t == 255) bsums[b] = sh[255];
}

// block-sum prefix folded in: each block wave-reduces the bsums it needs.
__global__ void k_scan_add_dinv(int* __restrict__ rowstart, const int* __restrict__ bsums,
                                const int* __restrict__ deg, float* __restrict__ dinv,
                                int* __restrict__ cursor) {
    __shared__ int soff;
    const int j = blockIdx.x >> 3;            // which 2048-block this 256-block lies in
    if (threadIdx.x < 64) {
        int v = ((int)threadIdx.x < j) ? bsums[threadIdx.x] : 0;   // j <= 48 < 64
        v += __shfl_xor(v, 1);  v += __shfl_xor(v, 2);  v += __shfl_xor(v, 4);
        v += __shfl_xor(v, 8);  v += __shfl_xor(v, 16); v += __shfl_xor(v, 32);
        if (threadIdx.x == 0) soff = v;
    }
    __syncthreads();
    int i = blockIdx.x * blockDim.x + threadIdx.x;
    if (i < N_NODES) {
        int r = rowstart[i] + soff;
        rowstart[i] = r;
        cursor[i] = r;
        dinv[i] = rsqrtf((float)(deg[i] + 1));
    }
    if (i == 0) rowstart[N_NODES] = N_EDGES;
}

// ---------------- CSR fill: (src,dst) pairs, dst-sorted (dst-slice partitioned) ----------------
__global__ __launch_bounds__(256) void k_fill(const uint4* __restrict__ dst4,
                                              const int* __restrict__ src32,
                                              int* __restrict__ cursor,
                                              int2* __restrict__ csr2) {
    const int g = blockIdx.x & 7, bb = blockIdx.x >> 3;
    const int lo = g * SLICE, hi = lo + SLICE;
    for (int q = bb * 256 + threadIdx.x; q < NQ; q += BPG * 256) {
        uint4 d = dst4[q];
        if ((int)d.x >= lo && (int)d.x < hi)
            csr2[atomicAdd(&cursor[d.x], 1)] = make_int2(src32[4 * q],     (int)d.x);
        if ((int)d.y >= lo && (int)d.y < hi)
            csr2[atomicAdd(&cursor[d.y], 1)] = make_int2(src32[4 * q + 1], (int)d.y);
        if ((int)d.z >= lo && (int)d.z < hi)
            csr2[atomicAdd(&cursor[d.z], 1)] = make_int2(src32[4 * q + 2], (int)d.z);
        if ((int)d.w >= lo && (int)d.w < hi)
            csr2[atomicAdd(&cursor[d.w], 1)] = make_int2(src32[4 * q + 3], (int)d.w);
    }
}

// ---------------- fused weight precompute ----------------
__global__ __launch_bounds__(256) void k_weights(const float* __restrict__ W1,
                                                 const float* __restrict__ W2,
                                                 const float* __restrict__ b1,
                                                 u16* __restrict__ Bt,
                                                 float* __restrict__ c1) {
    int idx = blockIdx.x * 256 + threadIdx.x;   // 4096 threads
    int l = idx & 63, c = (idx >> 6) & 3, kt = idx >> 8;
    int n = c * 16 + (l & 15);
    int k0 = kt * 32 + (l >> 4) * 8;
    float accs[8];
#pragma unroll
    for (int r = 0; r < 8; r++) accs[r] = 0.f;
    for (int jj = 0; jj < 128; jj++) {
        float w2v = W2[jj * 64 + n];
#pragma unroll
        for (int r = 0; r < 8; r++) accs[r] += W1[(k0 + r) * 128 + jj] * w2v;
    }
    u32 p[4];
#pragma unroll
    for (int j = 0; j < 4; j++)
        p[j] = (u32)f2bf(accs[2 * j]) | ((u32)f2bf(accs[2 * j + 1]) << 16);
    *(uint4*)&Bt[(long)idx * 8] = make_uint4(p[0], p[1], p[2], p[3]);

    if (blockIdx.x == 0 && threadIdx.x < 64) {
        int nn = threadIdx.x;
        float acc = 0.f;
        for (int j = 0; j < 128; j++) acc += b1[j] * W2[j * 64 + nn];
        c1[nn] = acc;
    }
}

// ---------------- GEMM: z'[M,64] = (bf16(x) @ Bt) * dinv[row], out bf16 ----------------

__global__ __launch_bounds__(256) void gemm_x(const float* __restrict__ A,
                                              const u16* __restrict__ Bt,
                                              const float* __restrict__ dinv,
                                              u16* __restrict__ C, int M) {
    constexpr int SA = 40;
    __shared__ u16 As[128 * SA];
    typedef __attribute__((ext_vector_type(8))) short v8s;
    typedef __attribute__((ext_vector_type(4))) float v4f;

    const int t = threadIdx.x;
    const int wave = t >> 6, lane = t & 63;
    const int m = lane & 15, quad = lane >> 4;
    const int row0 = blockIdx.x * 128;

    v4f acc[2][4];
#pragma unroll
    for (int i = 0; i < 2; i++)
#pragma unroll
        for (int c = 0; c < 4; c++)
#pragma unroll
            for (int r = 0; r < 4; r++) acc[i][c][r] = 0.0f;

    const int arow = t >> 1, ahalf = t & 1;
    const long aoff = (long)(row0 + arow) * 512;
    const bool arow_ok = (row0 + arow) < M;

    for (int kt = 0; kt < 16; ++kt) {
        const int kk0 = kt * 32 + ahalf * 16;
        float4 f0 = make_float4(0.f, 0.f, 0.f, 0.f), f1 = f0, f2 = f0, f3 = f0;
        if (arow_ok) {
            f0 = *(const float4*)&A[aoff + kk0];
            f1 = *(const float4*)&A[aoff + kk0 + 4];
            f2 = *(const float4*)&A[aoff + kk0 + 8];
            f3 = *(const float4*)&A[aoff + kk0 + 12];
        }
        uint4 w0, w1;
        w0.x = (u32)f2bf(f0.x) | ((u32)f2bf(f0.y) << 16);
        w0.y = (u32)f2bf(f0.z) | ((u32)f2bf(f0.w) << 16);
        w0.z = (u32)f2bf(f1.x) | ((u32)f2bf(f1.y) << 16);
        w0.w = (u32)f2bf(f1.z) | ((u32)f2bf(f1.w) << 16);
        w1.x = (u32)f2bf(f2.x) | ((u32)f2bf(f2.y) << 16);
        w1.y = (u32)f2bf(f2.z) | ((u32)f2bf(f2.w) << 16);
        w1.z = (u32)f2bf(f3.x) | ((u32)f2bf(f3.y) << 16);
        w1.w = (u32)f2bf(f3.z) | ((u32)f2bf(f3.w) << 16);
        *(uint4*)&As[arow * SA + ahalf * 16] = w0;
        *(uint4*)&As[arow * SA + ahalf * 16 + 8] = w1;
        __syncthreads();
        v8s a0 = *(const v8s*)&As[(wave * 32 + m) * SA + quad * 8];
        v8s a1 = *(const v8s*)&As[(wave * 32 + 16 + m) * SA + quad * 8];
#pragma unroll
        for (int c = 0; c < 4; c++) {
            v8s b = *(const v8s*)&Bt[(long)((kt * 4 + c) * 64 + lane) * 8];
            acc[0][c] = __builtin_amdgcn_mfma_f32_16x16x32_bf16(a0, b, acc[0][c], 0, 0, 0);
            acc[1][c] = __builtin_amdgcn_mfma_f32_16x16x32_bf16(a1, b, acc[1][c], 0, 0, 0);
        }
        __syncthreads();
    }
    // D layout: col = lane&15, row = quad*4 + r
#pragma unroll
    for (int i = 0; i < 2; i++)
#pragma unroll
        for (int r = 0; r < 4; r++) {
            int grow = row0 + wave * 32 + i * 16 + quad * 4 + r;
            if (grow < M) {
                float w = dinv[grow];
#pragma unroll
                for (int c = 0; c < 4; c++)
                    C[(long)grow * 64 + c * 16 + m] = f2bf(acc[i][c][r] * w);
            }
        }
}

// ---------------- aggregation pass A: edge-parallel LDS scatter ----------------
// Block owns dst-slice [n0, n0+NS); csr2 range for it is contiguous.
// Edge loop: 32 groups x 8 lanes; group gathers one 128B z' row per edge,
// ds_add_f32 into LDS accumulator. Epilogue: y' = dinv^2*(z'self + sum);
// sfac = dinv*(dinv + sum dinv[src]).

__global__ __launch_bounds__(256) void agg_a(const u16* __restrict__ zp,
                                             const float* __restrict__ dinv,
                                             const int* __restrict__ rowstart,
                                             const int2* __restrict__ csr2,
                                             u16* __restrict__ yp,
                                             float* __restrict__ sfac) {
    __shared__ float acc[NS * LDW];
    __shared__ float sdl[NS];
    const int tid = threadIdx.x;
    for (int i = tid; i < NS * LDW; i += 256) acc[i] = 0.f;
    if (tid < NS) sdl[tid] = 0.f;
    __syncthreads();

    const int n0 = blockIdx.x * NS;
    const int e0 = rowstart[n0], e1 = rowstart[n0 + NS];
    const int r = tid & 7, slot = tid >> 3;      // 32 groups of 8 lanes
    const uint4* z4 = (const uint4*)zp;

    for (int e = e0 + slot; e < e1; e += 64) {
        const int e2 = e + 32;
        const bool h2 = e2 < e1;
        int2 ed0 = csr2[e];
        int2 ed1;
        if (h2) ed1 = csr2[e2];
        uint4 d0 = z4[(long)ed0.x * 8 + r];
        uint4 d1;
        if (h2) d1 = z4[(long)ed1.x * 8 + r];
        float f[8];
        up8(d0, f);
        float* row = &acc[(ed0.y - n0) * LDW + r * 8];
#pragma unroll
        for (int j = 0; j < 8; j++) atomicAdd(&row[j], f[j]);
        if (r == 0) atomicAdd(&sdl[ed0.y - n0], dinv[ed0.x]);
        if (h2) {
            up8(d1, f);
            float* row1 = &acc[(ed1.y - n0) * LDW + r * 8];
#pragma unroll
            for (int j = 0; j < 8; j++) atomicAdd(&row1[j], f[j]);
            if (r == 0) atomicAdd(&sdl[ed1.y - n0], dinv[ed1.x]);
        }
    }
    __syncthreads();

    for (int nn = slot; nn < NS; nn += 32) {
        const int n = n0 + nn;
        const float w0 = dinv[n];
        const float w2 = w0 * w0;
        float f[8];
        up8(z4[(long)n * 8 + r], f);          // self-loop term z'[n]
        const float* row = &acc[nn * LDW + r * 8];
        uint4 o;
        o.x = (u32)f2bf((f[0] + row[0]) * w2) | ((u32)f2bf((f[1] + row[1]) * w2) << 16);
        o.y = (u32)f2bf((f[2] + row[2]) * w2) | ((u32)f2bf((f[3] + row[3]) * w2) << 16);
        o.z = (u32)f2bf((f[4] + row[4]) * w2) | ((u32)f2bf((f[5] + row[5]) * w2) << 16);
        o.w = (u32)f2bf((f[6] + row[6]) * w2) | ((u32)f2bf((f[7] + row[7]) * w2) << 16);
        ((uint4*)yp)[(long)n * 8 + r] = o;
        if (r == 0) sfac[n] = w0 * (w0 + sdl[nn]);
    }
}

// ---------------- aggregation pass B: edge-parallel LDS scatter ----------------
// out[n] = relu(dinv[n]*(y'self + sum y'[src]) + sfac[n]*c1 + b2), f32

__global__ __launch_bounds__(256) void agg_b(const u16* __restrict__ yp,
                                             const float* __restrict__ dinv,
                                             const int* __restrict__ rowstart,
                                             const int2* __restrict__ csr2,
                                             const float* __restrict__ sfac,
                                             const float* __restrict__ c1,
                                             const float* __restrict__ b2,
                                             float* __restrict__ out) {
    __shared__ float acc[NS * LDW];
    const int tid = threadIdx.x;
    for (int i = tid; i < NS * LDW; i += 256) acc[i] = 0.f;
    __syncthreads();

    const int n0 = blockIdx.x * NS;
    const int e0 = rowstart[n0], e1 = rowstart[n0 + NS];
    const int r = tid & 7, slot = tid >> 3;
    const uint4* y4 = (const uint4*)yp;

    for (int e = e0 + slot; e < e1; e += 64) {
        const int e2 = e + 32;
        const bool h2 = e2 < e1;
        int2 ed0 = csr2[e];
        int2 ed1;
        if (h2) ed1 = csr2[e2];
        uint4 d0 = y4[(long)ed0.x * 8 + r];
        uint4 d1;
        if (h2) d1 = y4[(long)ed1.x * 8 + r];
        float f[8];
        up8(d0, f);
        float* row = &acc[(ed0.y - n0) * LDW + r * 8];
#pragma unroll
        for (int j = 0; j < 8; j++) atomicAdd(&row[j], f[j]);
        if (h2) {
            up8(d1, f);
            float* row1 = &acc[(ed1.y - n0) * LDW + r * 8];
#pragma unroll
            for (int j = 0; j < 8; j++) atomicAdd(&row1[j], f[j]);
        }
    }
    __syncthreads();

    for (int nn = slot; nn < NS; nn += 32) {
        const int n = n0 + nn;
        const float w0 = dinv[n];
        const float sn = sfac[n];
        float f[8];
        up8(y4[(long)n * 8 + r], f);          // self-loop term y'[n]
        const float* row = &acc[nn * LDW + r * 8];
        float4 cA = ((const float4*)c1)[r * 2], cB = ((const float4*)c1)[r * 2 + 1];
        float4 bA = ((const float4*)b2)[r * 2], bB = ((const float4*)b2)[r * 2 + 1];
        float4 r0, r1;
        r0.x = fmaxf((f[0] + row[0]) * w0 + sn * cA.x + bA.x, 0.f);
        r0.y = fmaxf((f[1] + row[1]) * w0 + sn * cA.y + bA.y, 0.f);
        r0.z = fmaxf((f[2] + row[2]) * w0 + sn * cA.z + bA.z, 0.f);
        r0.w = fmaxf((f[3] + row[3]) * w0 + sn * cA.w + bA.w, 0.f);
        r1.x = fmaxf((f[4] + row[4]) * w0 + sn * cB.x + bB.x, 0.f);
        r1.y = fmaxf((f[5] + row[5]) * w0 + sn * cB.y + bB.y, 0.f);
        r1.z = fmaxf((f[6] + row[6]) * w0 + sn * cB.z + bB.z, 0.f);
        r1.w = fmaxf((f[7] + row[7]) * w0 + sn * cB.w + bB.w, 0.f);
        ((float4*)out)[(long)n * 16 + r * 2]     = r0;
        ((float4*)out)[(long)n * 16 + r * 2 + 1] = r1;
    }
}

// ---------------- host launch ----------------

extern "C" void kernel_launch(void* const* d_in, const int* in_sizes, int n_in,
                              void* d_out, int out_size, void* d_ws, size_t ws_size,
                              hipStream_t stream) {
    const float* x  = (const float*)d_in[0];
    const u32*   ei = (const u32*)d_in[1];
    const float* W1 = (const float*)d_in[2];
    const float* b1 = (const float*)d_in[3];
    const float* W2 = (const float*)d_in[4];
    const float* b2 = (const float*)d_in[5];
    float* out = (float*)d_out;

    char* ws = (char*)d_ws;
    size_t o = 0;
    auto alloc = [&](size_t bytes) -> char* {
        char* p = ws + o;
        o = (o + bytes + 255) & ~(size_t)255;
        return p;
    };
    int*   deg      = (int*)  alloc(N_NODES * 4);
    float* dinv     = (float*)alloc(N_NODES * 4);
    int*   rowstart = (int*)  alloc((N_NODES + 1) * 4);
    int*   cursor   = (int*)  alloc(N_NODES * 4);
    int*   bsums    = (int*)  alloc(64 * 4);
    u16*   Bt       = (u16*)  alloc(512 * 64 * 2);
    float* c1       = (float*)alloc(64 * 4);
    float* sfac     = (float*)alloc(N_NODES * 4);
    uint4* src4     = (uint4*)alloc((size_t)N_EDGES * 4);
    uint4* dst4     = (uint4*)alloc((size_t)N_EDGES * 4);
    int2*  csr2     = (int2*) alloc((size_t)N_EDGES * 8);
    u16*   z        = (u16*)  alloc((size_t)N_NODES * 64 * 2);
    u16*   y        = (u16*)  alloc((size_t)N_NODES * 64 * 2);
    (void)ws_size;

    hipMemsetAsync(deg, 0, N_NODES * 4, stream);

    const int NB = (N_NODES + 255) / 256;
    const int CQ = (NQ + 255) / 256;                 // 1563

    k_convert<<<CQ, 256, 0, stream>>>(ei, src4, dst4);
    k_degree<<<8 * BPG, 256, 0, stream>>>(dst4, deg);
    k_scan_part<<<(N_NODES + 2047) / 2048, 256, 0, stream>>>(deg, rowstart, bsums);
    k_scan_add_dinv<<<NB, 256, 0, stream>>>(rowstart, bsums, deg, dinv, cursor);
    k_fill<<<8 * BPG, 256, 0, stream>>>(dst4, (const int*)src4, cursor, csr2);

    k_weights<<<16, 256, 0, stream>>>(W1, W2, b1, Bt, c1);

    gemm_x<<<(N_NODES + 127) / 128, 256, 0, stream>>>(x, Bt, dinv, z, N_NODES);
    agg_a<<<NSLICES, 256, 0, stream>>>(z, dinv, rowstart, csr2, y, sfac);
    agg_b<<<NSLICES, 256, 0, stream>>>(y, dinv, rowstart, csr2, sfac, c1, b2, out);
}

// Round 5
// 589.610 us; speedup vs baseline: 2.6745x; 2.6745x over previous
//
#include <hip/hip_runtime.h>
#include <hip/hip_bf16.h>

typedef unsigned short u16;
typedef unsigned int   u32;

#define N_NODES 100000
#define N_EDGES 1600000
#define NQ      (N_EDGES / 4)     // 400000 uint4 quads per endpoint array
#define SLICE   12500             // N_NODES / 8
#define BPG     96                // blocks per dst-slice group in build kernels

__device__ __forceinline__ float bf2f(u16 u) {
    union { u32 i; float f; } c; c.i = ((u32)u) << 16; return c.f;
}
__device__ __forceinline__ u16 f2bf(float f) {
    union { float f; u32 i; } c; c.f = f;
    u32 u = c.i;
    u += 0x7fffu + ((u >> 16) & 1u);   // RNE
    return (u16)(u >> 16);
}
__device__ __forceinline__ void acc8(uint4 d, float* a) {
    a[0] += bf2f((u16)(d.x & 0xffffu)); a[1] += bf2f((u16)(d.x >> 16));
    a[2] += bf2f((u16)(d.y & 0xffffu)); a[3] += bf2f((u16)(d.y >> 16));
    a[4] += bf2f((u16)(d.z & 0xffffu)); a[5] += bf2f((u16)(d.z >> 16));
    a[6] += bf2f((u16)(d.w & 0xffffu)); a[7] += bf2f((u16)(d.w >> 16));
}

// ---------------- flatten edge_index to int32 src/dst (dtype probe inlined) ----------------
__global__ __launch_bounds__(256) void k_convert(const u32* __restrict__ ei,
                                                 uint4* __restrict__ src4,
                                                 uint4* __restrict__ dst4) {
    __shared__ int sflag;
    if (threadIdx.x == 0) {
        u32 h = ei[1] | ei[3] | ei[5] | ei[7];
        sflag = (h == 0u) ? 1 : 0;   // int64 layout: (lo,hi) pairs, hi==0
    }
    __syncthreads();
    int q = blockIdx.x * 256 + threadIdx.x;
    if (q >= NQ) return;
    const uint4* e4 = (const uint4*)ei;
    if (sflag) {
        uint4 a = e4[2 * q],          b = e4[2 * q + 1];
        src4[q] = make_uint4(a.x, a.z, b.x, b.z);
        uint4 c = e4[2 * NQ + 2 * q], d = e4[2 * NQ + 2 * q + 1];
        dst4[q] = make_uint4(c.x, c.z, d.x, d.z);
    } else {
        src4[q] = e4[q];
        dst4[q] = e4[NQ + q];
    }
}

// ---------------- degree (dst-slice partitioned; slice = blockIdx&7 ~ XCD) ----------------
__global__ __launch_bounds__(256) void k_degree(const uint4* __restrict__ dst4,
                                                int* __restrict__ deg) {
    const int g = blockIdx.x & 7, bb = blockIdx.x >> 3;
    const int lo = g * SLICE, hi = lo + SLICE;
    for (int q = bb * 256 + threadIdx.x; q < NQ; q += BPG * 256) {
        uint4 d = dst4[q];
        if ((int)d.x >= lo && (int)d.x < hi) atomicAdd(&deg[d.x], 1);
        if ((int)d.y >= lo && (int)d.y < hi) atomicAdd(&deg[d.y], 1);
        if ((int)d.z >= lo && (int)d.z < hi) atomicAdd(&deg[d.z], 1);
        if ((int)d.w >= lo && (int)d.w < hi) atomicAdd(&deg[d.w], 1);
    }
}

// ---------------- exclusive scan over degrees ----------------
__global__ void k_scan_part(const int* __restrict__ deg, int* __restrict__ rowstart,
                            int* __restrict__ bsums) {
    __shared__ int sh[256];
    const int t = threadIdx.x, b = blockIdx.x;
    const int base = b * 2048 + t * 8;
    int v[8]; int s = 0;
#pragma unroll
    for (int i = 0; i < 8; i++) {
        int idx = base + i;
        v[i] = (idx < N_NODES) ? deg[idx] : 0;
        s += v[i];
    }
    sh[t] = s;
    __syncthreads();
    for (int d = 1; d < 256; d <<= 1) {
        int x = (t >= d) ? sh[t - d] : 0;
        __syncthreads();
        sh[t] += x;
        __syncthreads();
    }
    int acc = sh[t] - s;
#pragma unroll
    for (int i = 0; i < 8; i++) {
        int idx = base + i;
        if (idx < N_NODES) rowstart[idx] = acc;
        acc += v[i];
    }
    if (t == 255) bsums[b] = sh[255];
}

// block-sum prefix folded in: each block wave-reduces the bsums it needs.
__global__ void k_scan_add_dinv(int* __restrict__ rowstart, const int* __restrict__ bsums,
                                const int* __restrict__ deg, float* __restrict__ dinv,
                                int* __restrict__ cursor) {
    __shared__ int soff;
    const int j = blockIdx.x >> 3;            // which 2048-block this 256-block lies in
    if (threadIdx.x < 64) {
        int v = ((int)threadIdx.x < j) ? bsums[threadIdx.x] : 0;   // j <= 48 < 64
        v += __shfl_xor(v, 1);  v += __shfl_xor(v, 2);  v += __shfl_xor(v, 4);
        v += __shfl_xor(v, 8);  v += __shfl_xor(v, 16); v += __shfl_xor(v, 32);
        if (threadIdx.x == 0) soff = v;
    }
    __syncthreads();
    int i = blockIdx.x * blockDim.x + threadIdx.x;
    if (i < N_NODES) {
        int r = rowstart[i] + soff;
        rowstart[i] = r;
        cursor[i] = r;
        dinv[i] = rsqrtf((float)(deg[i] + 1));
    }
    if (i == 0) rowstart[N_NODES] = N_EDGES;
}

// ---------------- CSR fill (dst-slice partitioned) ----------------
__global__ __launch_bounds__(256) void k_fill(const uint4* __restrict__ dst4,
                                              const int* __restrict__ src32,
                                              int* __restrict__ cursor,
                                              int* __restrict__ csr) {
    const int g = blockIdx.x & 7, bb = blockIdx.x >> 3;
    const int lo = g * SLICE, hi = lo + SLICE;
    for (int q = bb * 256 + threadIdx.x; q < NQ; q += BPG * 256) {
        uint4 d = dst4[q];
        if ((int)d.x >= lo && (int)d.x < hi) csr[atomicAdd(&cursor[d.x], 1)] = src32[4 * q];
        if ((int)d.y >= lo && (int)d.y < hi) csr[atomicAdd(&cursor[d.y], 1)] = src32[4 * q + 1];
        if ((int)d.z >= lo && (int)d.z < hi) csr[atomicAdd(&cursor[d.z], 1)] = src32[4 * q + 2];
        if ((int)d.w >= lo && (int)d.w < hi) csr[atomicAdd(&cursor[d.w], 1)] = src32[4 * q + 3];
    }
}

// ---------------- fused weight precompute ----------------
// Bt fragments computed directly from W1@W2 (no W12f round-trip); c1 = b1@W2 by block 0.
__global__ __launch_bounds__(256) void k_weights(const float* __restrict__ W1,
                                                 const float* __restrict__ W2,
                                                 const float* __restrict__ b1,
                                                 u16* __restrict__ Bt,
                                                 float* __restrict__ c1) {
    int idx = blockIdx.x * 256 + threadIdx.x;   // 4096 threads
    int l = idx & 63, c = (idx >> 6) & 3, kt = idx >> 8;
    int n = c * 16 + (l & 15);
    int k0 = kt * 32 + (l >> 4) * 8;
    float accs[8];
#pragma unroll
    for (int r = 0; r < 8; r++) accs[r] = 0.f;
    for (int jj = 0; jj < 128; jj++) {
        float w2v = W2[jj * 64 + n];
#pragma unroll
        for (int r = 0; r < 8; r++) accs[r] += W1[(k0 + r) * 128 + jj] * w2v;
    }
    u32 p[4];
#pragma unroll
    for (int j = 0; j < 4; j++)
        p[j] = (u32)f2bf(accs[2 * j]) | ((u32)f2bf(accs[2 * j + 1]) << 16);
    *(uint4*)&Bt[(long)idx * 8] = make_uint4(p[0], p[1], p[2], p[3]);

    if (blockIdx.x == 0 && threadIdx.x < 64) {
        int nn = threadIdx.x;
        float acc = 0.f;
        for (int j = 0; j < 128; j++) acc += b1[j] * W2[j * 64 + nn];
        c1[nn] = acc;
    }
}

// ---------------- GEMM: z'[M,64] = (bf16(x) @ Bt) * dinv[row], out bf16 ----------------

__global__ __launch_bounds__(256) void gemm_x(const float* __restrict__ A,
                                              const u16* __restrict__ Bt,
                                              const float* __restrict__ dinv,
                                              u16* __restrict__ C, int M) {
    constexpr int SA = 40;
    __shared__ u16 As[128 * SA];
    typedef __attribute__((ext_vector_type(8))) short v8s;
    typedef __attribute__((ext_vector_type(4))) float v4f;

    const int t = threadIdx.x;
    const int wave = t >> 6, lane = t & 63;
    const int m = lane & 15, quad = lane >> 4;
    const int row0 = blockIdx.x * 128;

    v4f acc[2][4];
#pragma unroll
    for (int i = 0; i < 2; i++)
#pragma unroll
        for (int c = 0; c < 4; c++)
#pragma unroll
            for (int r = 0; r < 4; r++) acc[i][c][r] = 0.0f;

    const int arow = t >> 1, ahalf = t & 1;
    const long aoff = (long)(row0 + arow) * 512;
    const bool arow_ok = (row0 + arow) < M;

    for (int kt = 0; kt < 16; ++kt) {
        const int kk0 = kt * 32 + ahalf * 16;
        float4 f0 = make_float4(0.f, 0.f, 0.f, 0.f), f1 = f0, f2 = f0, f3 = f0;
        if (arow_ok) {
            f0 = *(const float4*)&A[aoff + kk0];
            f1 = *(const float4*)&A[aoff + kk0 + 4];
            f2 = *(const float4*)&A[aoff + kk0 + 8];
            f3 = *(const float4*)&A[aoff + kk0 + 12];
        }
        uint4 w0, w1;
        w0.x = (u32)f2bf(f0.x) | ((u32)f2bf(f0.y) << 16);
        w0.y = (u32)f2bf(f0.z) | ((u32)f2bf(f0.w) << 16);
        w0.z = (u32)f2bf(f1.x) | ((u32)f2bf(f1.y) << 16);
        w0.w = (u32)f2bf(f1.z) | ((u32)f2bf(f1.w) << 16);
        w1.x = (u32)f2bf(f2.x) | ((u32)f2bf(f2.y) << 16);
        w1.y = (u32)f2bf(f2.z) | ((u32)f2bf(f2.w) << 16);
        w1.z = (u32)f2bf(f3.x) | ((u32)f2bf(f3.y) << 16);
        w1.w = (u32)f2bf(f3.z) | ((u32)f2bf(f3.w) << 16);
        *(uint4*)&As[arow * SA + ahalf * 16] = w0;
        *(uint4*)&As[arow * SA + ahalf * 16 + 8] = w1;
        __syncthreads();
        v8s a0 = *(const v8s*)&As[(wave * 32 + m) * SA + quad * 8];
        v8s a1 = *(const v8s*)&As[(wave * 32 + 16 + m) * SA + quad * 8];
#pragma unroll
        for (int c = 0; c < 4; c++) {
            v8s b = *(const v8s*)&Bt[(long)((kt * 4 + c) * 64 + lane) * 8];
            acc[0][c] = __builtin_amdgcn_mfma_f32_16x16x32_bf16(a0, b, acc[0][c], 0, 0, 0);
            acc[1][c] = __builtin_amdgcn_mfma_f32_16x16x32_bf16(a1, b, acc[1][c], 0, 0, 0);
        }
        __syncthreads();
    }
    // D layout: col = lane&15, row = quad*4 + r
#pragma unroll
    for (int i = 0; i < 2; i++)
#pragma unroll
        for (int r = 0; r < 4; r++) {
            int grow = row0 + wave * 32 + i * 16 + quad * 4 + r;
            if (grow < M) {
                float w = dinv[grow];
#pragma unroll
                for (int c = 0; c < 4; c++)
                    C[(long)grow * 64 + c * 16 + m] = f2bf(acc[i][c][r] * w);
            }
        }
}

// ---------------- aggregation pass A ----------------
// 8 groups x 8 lanes; each group gathers one 128B row (uint4/lane) per step, 4x unrolled
// (32 gather lines in flight per wave). Per-group accumulation order identical to the
// 2x-unrolled version (ascending i within g mod 8) -> bit-identical sums.
// y'[n] = dinv[n]^2 * (z'[n] + sum z'[csr]); sfac[n] = dinv[n]*(dinv[n] + sum dinv[csr])

__global__ __launch_bounds__(256) void agg_a(const u16* __restrict__ zp,
                                             const float* __restrict__ dinv,
                                             const int* __restrict__ rowstart,
                                             const int* __restrict__ csr,
                                             u16* __restrict__ yp,
                                             float* __restrict__ sfac) {
    const int wave = threadIdx.x >> 6, lane = threadIdx.x & 63;
    const int n = blockIdx.x * 4 + wave;
    const int g = lane >> 3, l = lane & 7;
    const uint4* z4 = (const uint4*)zp;
    float a[8] = {0.f, 0.f, 0.f, 0.f, 0.f, 0.f, 0.f, 0.f};
    float sd = 0.f;
    const float w0 = dinv[n];
    if (g == 0) {
        acc8(z4[(long)n * 8 + l], a);
        sd = w0;
    }
    const int i1 = rowstart[n + 1];
    int i = rowstart[n] + g;
    for (; i + 24 < i1; i += 32) {
        int s0 = csr[i], s1 = csr[i + 8], s2 = csr[i + 16], s3 = csr[i + 24];
        uint4 d0 = z4[(long)s0 * 8 + l];
        uint4 d1 = z4[(long)s1 * 8 + l];
        uint4 d2 = z4[(long)s2 * 8 + l];
        uint4 d3 = z4[(long)s3 * 8 + l];
        sd += dinv[s0] + dinv[s1];
        sd += dinv[s2] + dinv[s3];
        acc8(d0, a); acc8(d1, a); acc8(d2, a); acc8(d3, a);
    }
    for (; i < i1; i += 8) {
        int s = csr[i];
        uint4 d = z4[(long)s * 8 + l];
        sd += dinv[s];
        acc8(d, a);
    }
#pragma unroll
    for (int j = 0; j < 8; j++) {
        a[j] += __shfl_xor(a[j], 8);
        a[j] += __shfl_xor(a[j], 16);
        a[j] += __shfl_xor(a[j], 32);
    }
    sd += __shfl_xor(sd, 8); sd += __shfl_xor(sd, 16); sd += __shfl_xor(sd, 32);
    if (g == 0) {
        float w2 = w0 * w0;
        uint4 o;
        o.x = (u32)f2bf(a[0] * w2) | ((u32)f2bf(a[1] * w2) << 16);
        o.y = (u32)f2bf(a[2] * w2) | ((u32)f2bf(a[3] * w2) << 16);
        o.z = (u32)f2bf(a[4] * w2) | ((u32)f2bf(a[5] * w2) << 16);
        o.w = (u32)f2bf(a[6] * w2) | ((u32)f2bf(a[7] * w2) << 16);
        ((uint4*)yp)[(long)n * 8 + l] = o;
        if (l == 0) sfac[n] = w0 * sd;
    }
}

// ---------------- aggregation pass B ----------------
// out[n] = relu(dinv[n]*(y'[n] + sum y'[csr]) + sfac[n]*c1 + b2), f32

__global__ __launch_bounds__(256) void agg_b(const u16* __restrict__ yp,
                                             const float* __restrict__ dinv,
                                             const int* __restrict__ rowstart,
                                             const int* __restrict__ csr,
                                             const float* __restrict__ sfac,
                                             const float* __restrict__ c1,
                                             const float* __restrict__ b2,
                                             float* __restrict__ out) {
    const int wave = threadIdx.x >> 6, lane = threadIdx.x & 63;
    const int n = blockIdx.x * 4 + wave;
    const int g = lane >> 3, l = lane & 7;
    const uint4* y4 = (const uint4*)yp;
    float a[8] = {0.f, 0.f, 0.f, 0.f, 0.f, 0.f, 0.f, 0.f};
    if (g == 0) acc8(y4[(long)n * 8 + l], a);
    const int i1 = rowstart[n + 1];
    int i = rowstart[n] + g;
    for (; i + 24 < i1; i += 32) {
        int s0 = csr[i], s1 = csr[i + 8], s2 = csr[i + 16], s3 = csr[i + 24];
        uint4 d0 = y4[(long)s0 * 8 + l];
        uint4 d1 = y4[(long)s1 * 8 + l];
        uint4 d2 = y4[(long)s2 * 8 + l];
        uint4 d3 = y4[(long)s3 * 8 + l];
        acc8(d0, a); acc8(d1, a); acc8(d2, a); acc8(d3, a);
    }
    for (; i < i1; i += 8) {
        uint4 d = y4[(long)csr[i] * 8 + l];
        acc8(d, a);
    }
#pragma unroll
    for (int j = 0; j < 8; j++) {
        a[j] += __shfl_xor(a[j], 8);
        a[j] += __shfl_xor(a[j], 16);
        a[j] += __shfl_xor(a[j], 32);
    }
    if (g == 0) {
        const float w0 = dinv[n];
        const float sn = sfac[n];
        float4 c0 = ((const float4*)c1)[2 * l], c4 = ((const float4*)c1)[2 * l + 1];
        float4 b0 = ((const float4*)b2)[2 * l], b4 = ((const float4*)b2)[2 * l + 1];
        float4 r0, r1;
        r0.x = fmaxf(a[0] * w0 + sn * c0.x + b0.x, 0.f);
        r0.y = fmaxf(a[1] * w0 + sn * c0.y + b0.y, 0.f);
        r0.z = fmaxf(a[2] * w0 + sn * c0.z + b0.z, 0.f);
        r0.w = fmaxf(a[3] * w0 + sn * c0.w + b0.w, 0.f);
        r1.x = fmaxf(a[4] * w0 + sn * c4.x + b4.x, 0.f);
        r1.y = fmaxf(a[5] * w0 + sn * c4.y + b4.y, 0.f);
        r1.z = fmaxf(a[6] * w0 + sn * c4.z + b4.z, 0.f);
        r1.w = fmaxf(a[7] * w0 + sn * c4.w + b4.w, 0.f);
        ((float4*)out)[(long)n * 16 + 2 * l]     = r0;
        ((float4*)out)[(long)n * 16 + 2 * l + 1] = r1;
    }
}

// ---------------- host launch ----------------

extern "C" void kernel_launch(void* const* d_in, const int* in_sizes, int n_in,
                              void* d_out, int out_size, void* d_ws, size_t ws_size,
                              hipStream_t stream) {
    const float* x  = (const float*)d_in[0];
    const u32*   ei = (const u32*)d_in[1];
    const float* W1 = (const float*)d_in[2];
    const float* b1 = (const float*)d_in[3];
    const float* W2 = (const float*)d_in[4];
    const float* b2 = (const float*)d_in[5];
    float* out = (float*)d_out;

    char* ws = (char*)d_ws;
    size_t o = 0;
    auto alloc = [&](size_t bytes) -> char* {
        char* p = ws + o;
        o = (o + bytes + 255) & ~(size_t)255;
        return p;
    };
    int*   deg      = (int*)  alloc(N_NODES * 4);
    float* dinv     = (float*)alloc(N_NODES * 4);
    int*   rowstart = (int*)  alloc((N_NODES + 1) * 4);
    int*   cursor   = (int*)  alloc(N_NODES * 4);
    int*   bsums    = (int*)  alloc(64 * 4);
    u16*   Bt       = (u16*)  alloc(512 * 64 * 2);
    float* c1       = (float*)alloc(64 * 4);
    float* sfac     = (float*)alloc(N_NODES * 4);
    uint4* src4     = (uint4*)alloc((size_t)N_EDGES * 4);
    uint4* dst4     = (uint4*)alloc((size_t)N_EDGES * 4);
    int*   csr      = (int*)  alloc((size_t)N_EDGES * 4);
    u16*   z        = (u16*)  alloc((size_t)N_NODES * 64 * 2);
    u16*   y        = (u16*)  alloc((size_t)N_NODES * 64 * 2);
    (void)ws_size;

    hipMemsetAsync(deg, 0, N_NODES * 4, stream);

    const int NB = (N_NODES + 255) / 256;
    const int CQ = (NQ + 255) / 256;                 // 1563

    k_convert<<<CQ, 256, 0, stream>>>(ei, src4, dst4);
    k_degree<<<8 * BPG, 256, 0, stream>>>(dst4, deg);
    k_scan_part<<<(N_NODES + 2047) / 2048, 256, 0, stream>>>(deg, rowstart, bsums);
    k_scan_add_dinv<<<NB, 256, 0, stream>>>(rowstart, bsums, deg, dinv, cursor);
    k_fill<<<8 * BPG, 256, 0, stream>>>(dst4, (const int*)src4, cursor, csr);

    k_weights<<<16, 256, 0, stream>>>(W1, W2, b1, Bt, c1);

    gemm_x<<<(N_NODES + 127) / 128, 256, 0, stream>>>(x, Bt, dinv, z, N_NODES);
    agg_a<<<N_NODES / 4, 256, 0, stream>>>(z, dinv, rowstart, csr, y, sfac);
    agg_b<<<N_NODES / 4, 256, 0, stream>>>(y, dinv, rowstart, csr, sfac, c1, b2, out);
}